// Round 16
// baseline (92.474 us; speedup 1.0000x reference)
//
#include <hip/hip_runtime.h>

#define B_ 4
#define C_ 128
#define H_ 128
#define W_ 256
#define HW_ (H_ * W_)
#define ND 81
#define TH 4          // output rows per block
#define TW 16         // output cols per block
#define HR2 12        // f2 halo rows (TH + 8)
#define KC 32         // channels per chunk (= MFMA K)
#define NCHUNK (C_ / KC)
#define NTHREADS 256
#define F1OFF (HR2 * 32 * 64)   // f2 region: 384 px * 64 B = 24576

typedef short bf16x8 __attribute__((ext_vector_type(8)));
typedef float f32x4 __attribute__((ext_vector_type(4)));
typedef float f32x4v __attribute__((ext_vector_type(4)));
typedef unsigned int u32x4 __attribute__((ext_vector_type(4)));

// Swizzle (HW-verified R1/R3-R15): XOR bits 4..6 of full byte addr by
// (r&7)<<4, r = px>>1 in bits >=7. Bijective. MFMA-read linearity: dy step
// (+32 px -> r+16) and t step (+16 px -> r+8) keep (r&7) -> single vaddr
// + imm offsets dy*2048 / +1024.
__device__ __forceinline__ int swz(int px, int byteInHalf) {
    int r = px >> 1;
    int base = (r << 7) + ((px & 1) << 6) + byteInHalf;
    return base ^ ((r & 7) << 4);
}

__device__ __forceinline__ unsigned int cvt_pk_bf16(float a, float b) {
    unsigned int r;
    asm("v_cvt_pk_bf16_f32 %0, %1, %2" : "=v"(r) : "v"(a), "v"(b));
    return r;
}

// ss += lo(u)^2 + hi(u)^2 (one VOP3P instr, R10-verified).
__device__ __forceinline__ void dot2_sq(unsigned int u, float& ss) {
    asm("v_dot2_f32_bf16 %0, %1, %1, %0" : "+v"(ss) : "v"(u));
}

// Barrier WITHOUT vmcnt drain (R6-verified).
#define BARRIER()                                             \
    do {                                                      \
        asm volatile("s_waitcnt lgkmcnt(0)" ::: "memory");    \
        __builtin_amdgcn_s_barrier();                         \
    } while (0)

__global__ __launch_bounds__(NTHREADS)
void corr81_kernel(const float* __restrict__ f1g, const float* __restrict__ f2g,
                   float* __restrict__ out) {
    // R16 TLP probe: small block (4 waves), single-buffer ~30 KB ->
    // 4 independent blocks/CU (vs 2 all prior rounds).
    __shared__ __align__(16) unsigned short f2s[HR2 * 32 * KC];   // 24576 B
    __shared__ __align__(16) unsigned short f1s[TH * TW * KC];    // 4096 B
    __shared__ float invn2[HR2 * 32];                             // 1536 B
    __shared__ float invn1[TH * TW];                              // 256 B

    const int tid  = threadIdx.x;
    const int lane = tid & 63;
    const int wave = tid >> 6;            // 0..3 -> output row within tile
    const int col  = lane & 15;
    const int quad = lane >> 4;

    // XCD-aware swizzle (T1). Bijective: 2048 = 8 * 256.
    const int flat = blockIdx.x + 16 * blockIdx.y + 512 * blockIdx.z;
    const int orig = (flat & 7) * 256 + (flat >> 3);
    const int w0 = (orig & 15) * TW;
    const int h0 = ((orig >> 4) & 31) * TH;
    const int b  = orig >> 9;
    const float* f2base = f2g + (size_t)b * C_ * HW_;
    const float* f1base = f1g + (size_t)b * C_ * HW_;

    // f2 staging: 6 row-tasks/thread (rows r = 2i+rq), A-half i 0..2,
    // B-half i 3..5 (JIT).  g2 = col-group, cp2 = channel pair.
    const int g2  = tid & 7;
    const int cp2 = (tid >> 3) & 15;
    const int rq  = tid >> 7;             // 0..1
    const int gw2 = w0 - 4 + g2 * 4;
    const bool colok2 = (gw2 >= 0) && (gw2 < W_);

    bool vrow[6];
    int off2[6];
#pragma unroll
    for (int i = 0; i < 6; ++i) {
        int r  = i * 2 + rq;
        int gh = h0 - 4 + r;
        vrow[i] = colok2 && (gh >= 0) && (gh < H_);
        off2[i] = cp2 * 2 * HW_ + (vrow[i] ? (gh * W_ + gw2) : 0);
    }

    // f1 staging: one task/thread
    const int g1  = tid & 3;
    const int cp1 = (tid >> 2) & 15;
    const int r1  = tid >> 6;
    const int off1 = cp1 * 2 * HW_ + (h0 + r1) * W_ + (w0 + g1 * 4);

    // MFMA fragment bases (single vaddr + imm offsets)
    const int rb2 = swz(wave * 32 + col, quad * 16);
    const int rb1 = swz(wave * 16 + col, quad * 16);
    const char* f2c = (const char*)&f2s[0];
    const char* f1c = (const char*)&f1s[0];

    f32x4 acc[9][2];
#pragma unroll
    for (int d = 0; d < 9; ++d) { acc[d][0] = (f32x4)0.f; acc[d][1] = (f32x4)0.f; }

    float ss2a = 0.f, ss2b = 0.f, ss1 = 0.f;
    // prefetch regs, zeroed once (invalid lanes never overwritten)
    f32x4v A0[3] = {}, A1[3] = {}, BB0[3] = {}, BB1[3] = {}, F0, F1v;

#define ISSUE_A(kc0)                                                            \
    {                                                                           \
        const float* bk2 = f2base + (size_t)(kc0) * HW_;                        \
        _Pragma("unroll")                                                       \
        for (int i = 0; i < 3; ++i)                                             \
            if (vrow[i]) {                                                      \
                A0[i] = *(const f32x4v*)(bk2 + off2[i]);                        \
                A1[i] = *(const f32x4v*)(bk2 + off2[i] + HW_);                  \
            }                                                                   \
    }

#define ISSUE_B(kc0)                                                            \
    {                                                                           \
        const float* bk2 = f2base + (size_t)(kc0) * HW_;                        \
        _Pragma("unroll")                                                       \
        for (int i = 0; i < 3; ++i)                                             \
            if (vrow[i + 3]) {                                                  \
                BB0[i] = *(const f32x4v*)(bk2 + off2[i + 3]);                   \
                BB1[i] = *(const f32x4v*)(bk2 + off2[i + 3] + HW_);             \
            }                                                                   \
    }

#define ISSUE_F1(kc0)                                                           \
    {                                                                           \
        const float* bk1 = f1base + (size_t)(kc0) * HW_;                        \
        F0  = *(const f32x4v*)(bk1 + off1);                                     \
        F1v = *(const f32x4v*)(bk1 + off1 + HW_);                               \
    }

#define PACK_A()                                                                \
    {                                                                           \
        char* w2 = (char*)&f2s[0];                                              \
        _Pragma("unroll")                                                       \
        for (int i = 0; i < 3; ++i) {                                           \
            int r = i * 2 + rq;                                                 \
            _Pragma("unroll")                                                   \
            for (int j = 0; j < 4; ++j) {                                       \
                int px = r * 32 + g2 * 4 + j;                                   \
                *(unsigned int*)(w2 + swz(px, cp2 * 4)) =                       \
                    cvt_pk_bf16(A0[i][j], A1[i][j]);                            \
            }                                                                   \
        }                                                                       \
    }

#define PACK_B()                                                                \
    {                                                                           \
        char* w2 = (char*)&f2s[0];                                              \
        _Pragma("unroll")                                                       \
        for (int i = 0; i < 3; ++i) {                                           \
            int r = (i + 3) * 2 + rq;                                           \
            _Pragma("unroll")                                                   \
            for (int j = 0; j < 4; ++j) {                                       \
                int px = r * 32 + g2 * 4 + j;                                   \
                *(unsigned int*)(w2 + swz(px, cp2 * 4)) =                       \
                    cvt_pk_bf16(BB0[i][j], BB1[i][j]);                          \
            }                                                                   \
        }                                                                       \
    }

#define PACK_F1()                                                               \
    {                                                                           \
        char* w1 = (char*)&f1s[0];                                              \
        _Pragma("unroll")                                                       \
        for (int j = 0; j < 4; ++j) {                                           \
            int px = r1 * 16 + g1 * 4 + j;                                      \
            *(unsigned int*)(w1 + swz(px, cp1 * 4)) = cvt_pk_bf16(F0[j], F1v[j]);\
        }                                                                       \
    }

#define MFMA_PHASE()                                                            \
    {                                                                           \
        bf16x8 af = *(const bf16x8*)(f1c + rb1);                                \
        _Pragma("unroll")                                                       \
        for (int dy = 0; dy < 9; ++dy) {                                        \
            bf16x8 b0 = *(const bf16x8*)(f2c + rb2 + dy * 2048);                \
            bf16x8 b1 = *(const bf16x8*)(f2c + rb2 + dy * 2048 + 1024);         \
            acc[dy][0] = __builtin_amdgcn_mfma_f32_16x16x32_bf16(af, b0, acc[dy][0], 0, 0, 0); \
            acc[dy][1] = __builtin_amdgcn_mfma_f32_16x16x32_bf16(af, b1, acc[dy][1], 0, 0, 0); \
        }                                                                       \
    }

    // NORM: thread owns f2 px tid (+ px 256+tid for tid<128) + 1 f1 slot.
#define NORM_PHASE()                                                            \
    {                                                                           \
        _Pragma("unroll")                                                       \
        for (int j = 0; j < 4; ++j) {                                           \
            u32x4 v = *(const u32x4*)(f2c + swz(tid, j * 16));                  \
            dot2_sq(v[0], ss2a); dot2_sq(v[1], ss2a);                           \
            dot2_sq(v[2], ss2a); dot2_sq(v[3], ss2a);                           \
        }                                                                       \
        if (tid < 128) {                                                        \
            _Pragma("unroll")                                                   \
            for (int j = 0; j < 4; ++j) {                                       \
                u32x4 v = *(const u32x4*)(f2c + swz(256 + tid, j * 16));        \
                dot2_sq(v[0], ss2b); dot2_sq(v[1], ss2b);                       \
                dot2_sq(v[2], ss2b); dot2_sq(v[3], ss2b);                       \
            }                                                                   \
        }                                                                       \
        u32x4 v = *(const u32x4*)(f1c + swz(tid >> 2, (tid & 3) * 16));         \
        dot2_sq(v[0], ss1); dot2_sq(v[1], ss1);                                 \
        dot2_sq(v[2], ss1); dot2_sq(v[3], ss1);                                 \
    }

    // ---- prologue: stage chunk 0, prefetch A/f1 of chunk 1 ----
    ISSUE_A(0); ISSUE_B(0); ISSUE_F1(0);
    PACK_A(); PACK_B(); PACK_F1();
    ISSUE_A(KC); ISSUE_F1(KC);
    BARRIER();

    // ---- main: single buffer, 2 barriers/chunk; B-half JIT ----
#pragma unroll
    for (int k = 0; k < NCHUNK; ++k) {
        if (k < NCHUNK - 1) ISSUE_B((k + 1) * KC);   // in flight across MFMA
        MFMA_PHASE();
        NORM_PHASE();
        if (k == NCHUNK - 1) {
            invn2[tid] = 1.f / fmaxf(sqrtf(ss2a), 1e-12f);
            if (tid < 128) invn2[256 + tid] = 1.f / fmaxf(sqrtf(ss2b), 1e-12f);
            float t1 = ss1 + __shfl_xor(ss1, 1);
            t1 += __shfl_xor(t1, 2);
            if ((tid & 3) == 0) invn1[tid >> 2] = 1.f / fmaxf(sqrtf(t1), 1e-12f);
        }
        BARRIER();                        // chunk-k reads complete
        if (k < NCHUNK - 1) {
            PACK_A(); PACK_F1();          // prefetched last interval
            PACK_B();                     // JIT (issued this chunk's MFMA interval)
            if (k < NCHUNK - 2) { ISSUE_A((k + 2) * KC); ISSUE_F1((k + 2) * KC); }
            BARRIER();                    // chunk-(k+1) writes complete
        }
    }

    // ---- epilogue: band extraction (R10-verified mapping) ----
    const int hOut = h0 + wave;
    float* outB = out + (size_t)b * ND * HW_ + (size_t)hOut * W_;
    const float scale = 1.f / (float)C_;

#pragma unroll
    for (int dy = 0; dy < 9; ++dy) {
        int hr = wave + dy;
#pragma unroll
        for (int t = 0; t < 2; ++t) {
            float i2 = invn2[hr * 32 + t * 16 + col];
#pragma unroll
            for (int r = 0; r < 4; ++r) {
                int row = quad * 4 + r;
                int dx = t * 16 + col - row;
                if (dx >= 0 && dx <= 8) {
                    float v = acc[dy][t][r] * invn1[wave * 16 + row] * i2 * scale;
                    v = (v >= 0.f) ? v : 0.1f * v;
                    outB[(size_t)(dy * 9 + dx) * HW_ + (w0 + row)] = v;
                }
            }
        }
    }
#undef ISSUE_A
#undef ISSUE_B
#undef ISSUE_F1
#undef PACK_A
#undef PACK_B
#undef PACK_F1
#undef MFMA_PHASE
#undef NORM_PHASE
}

extern "C" void kernel_launch(void* const* d_in, const int* in_sizes, int n_in,
                              void* d_out, int out_size, void* d_ws, size_t ws_size,
                              hipStream_t stream) {
    const float* f1 = (const float*)d_in[0];
    const float* f2 = (const float*)d_in[1];
    float* out = (float*)d_out;
    dim3 grid(W_ / TW, H_ / TH, B_);   // 16 x 32 x 4 = 2048 blocks
    corr81_kernel<<<grid, NTHREADS, 0, stream>>>(f1, f2, out);
}

// Round 17
// 64.153 us; speedup vs baseline: 1.4415x; 1.4415x over previous
//
#include <hip/hip_runtime.h>

#define B_ 4
#define C_ 128
#define H_ 128
#define W_ 256
#define HW_ (H_ * W_)
#define ND 81
#define TH 8          // output rows per block
#define TW 16         // output cols per block
#define HR 16         // f2 halo rows  (TH + 8)
#define WCOL 32       // f2 halo cols
#define KC 32         // channels per LDS chunk (= MFMA K)
#define NCHUNK (C_ / KC)
#define NTHREADS 512

typedef short bf16x8 __attribute__((ext_vector_type(8)));
typedef float f32x4 __attribute__((ext_vector_type(4)));
typedef float f32x4v __attribute__((ext_vector_type(4)));
typedef unsigned int u32x4 __attribute__((ext_vector_type(4)));

// Swizzle (HW-verified R1/R3-R15): XOR bits 4..6 of the full byte address by
// (r & 7) << 4 where r = px>>1 lives in bits >=7. Bijective.
__device__ __forceinline__ int swz(int px, int byteInHalf) {
    int r = px >> 1;
    int base = (r << 7) + ((px & 1) << 6) + byteInHalf;
    return base ^ ((r & 7) << 4);
}

// Native packed fp32->bf16 convert (gfx950). A/B use the same packing so the
// MFMA dot is invariant to lo/hi order.
__device__ __forceinline__ unsigned int cvt_pk_bf16(float a, float b) {
    unsigned int r;
    asm("v_cvt_pk_bf16_f32 %0, %1, %2" : "=v"(r) : "v"(a), "v"(b));
    return r;
}

// ss += lo(u)^2 + hi(u)^2 in one VOP3P instruction (R10-verified).
__device__ __forceinline__ void dot2_sq(unsigned int u, float& ss) {
    asm("v_dot2_f32_bf16 %0, %1, %1, %0" : "+v"(ss) : "v"(u));
}

// Barrier WITHOUT vmcnt drain (R6-verified): LDS ordered, globals in flight.
#define BARRIER()                                             \
    do {                                                      \
        asm volatile("s_waitcnt lgkmcnt(0)" ::: "memory");    \
        __builtin_amdgcn_s_barrier();                         \
    } while (0)

// Best verified configuration (R10, 64.2 us). Session errata honored:
// no launch-bounds min-blocks hint (R7/R8), no wave stagger (R9), no
// pixel-major staging (R11), no LDS-transposed epilogue (R12), no wave
// specialization (R13), double- not single-buffer (R15), 512-thr not
// 256-thr blocks (R16).
__global__ __launch_bounds__(NTHREADS)
void corr81_kernel(const float* __restrict__ f1g, const float* __restrict__ f2g,
                   float* __restrict__ out) {
    // Double-buffered staging: exactly 80 KB -> 2 blocks/CU.
    __shared__ __align__(16) unsigned short f2s[2][HR * WCOL * KC];  // 2 x 32 KB
    __shared__ __align__(16) unsigned short f1s[2][TH * TW * KC];    // 2 x 8 KB
    // invn arrays overlay buf0 (hazard-free: buf0 last staged at k=1, last
    // read at k=2; invn written at k=3 after k=2's barrier; epilogue reads
    // after the final barrier).
    float* invn2 = (float*)&f2s[0][0];   // 512 floats
    float* invn1 = (float*)&f1s[0][0];   // 128 floats

    const int tid  = threadIdx.x;
    const int lane = tid & 63;
    const int wave = tid >> 6;            // 0..7 -> output row within tile
    const int col  = lane & 15;
    const int quad = lane >> 4;

    // XCD-aware block swizzle (T1, verified R4). Bijective: 1024 = 8*128.
    const int flat = blockIdx.x + 16 * blockIdx.y + 256 * blockIdx.z;
    const int orig = (flat & 7) * 128 + (flat >> 3);
    const int w0 = (orig & 15) * TW;
    const int h0 = ((orig >> 4) & 15) * TH;
    const int b  = orig >> 8;
    const size_t inBase = (size_t)b * C_ * HW_;

    // f2 staging: (i 0..3) x per-thread (g2, cp2, rq)
    const int g2  = tid & 7;
    const int cp2 = (tid >> 3) & 15;
    const int rq  = tid >> 7;
    const int gw2 = w0 - 4 + g2 * 4;
    const bool colok2 = (gw2 >= 0) && (gw2 < W_);

    // f1 staging: one float4-pair per thread
    const int g1  = tid & 3;
    const int cp1 = (tid >> 2) & 15;
    const int r1  = tid >> 6;
    const float* src1 = f1g + inBase + (size_t)(h0 + r1) * W_ + (w0 + g1 * 4);

    const int aOff = swz(wave * 16 + col, quad * 16);

    f32x4 acc[9][2];
#pragma unroll
    for (int d = 0; d < 9; ++d) {
        acc[d][0] = (f32x4)0.f;
        acc[d][1] = (f32x4)0.f;
    }

    float ss2 = 0.f, ss1 = 0.f;
    f32x4v A0[4], A1[4], B0, B1;

#define ISSUE_LOADS(kc0)                                                        \
    {                                                                           \
        _Pragma("unroll")                                                       \
        for (int i = 0; i < 4; ++i) {                                           \
            int r  = i * 4 + rq;                                                \
            int gh = h0 - 4 + r;                                                \
            if (colok2 && gh >= 0 && gh < H_) {                                 \
                const float* s = f2g + inBase + (size_t)((kc0) + cp2 * 2) * HW_ \
                                 + (size_t)gh * W_ + gw2;                       \
                A0[i] = *(const f32x4v*)s;                                      \
                A1[i] = *(const f32x4v*)(s + HW_);                              \
            } else {                                                            \
                A0[i] = (f32x4v)0.f;                                            \
                A1[i] = (f32x4v)0.f;                                            \
            }                                                                   \
        }                                                                       \
        const float* s = src1 + (size_t)((kc0) + cp1 * 2) * HW_;                \
        B0 = *(const f32x4v*)s;                                                 \
        B1 = *(const f32x4v*)(s + HW_);                                         \
    }

#define PACK_WRITE(buf)                                                         \
    {                                                                           \
        char* w2 = (char*)&f2s[(buf)][0];                                       \
        char* w1 = (char*)&f1s[(buf)][0];                                       \
        _Pragma("unroll")                                                       \
        for (int i = 0; i < 4; ++i) {                                           \
            int r = i * 4 + rq;                                                 \
            _Pragma("unroll")                                                   \
            for (int j = 0; j < 4; ++j) {                                       \
                int px = r * 32 + g2 * 4 + j;                                   \
                *(unsigned int*)(w2 + swz(px, cp2 * 4)) =                       \
                    cvt_pk_bf16(A0[i][j], A1[i][j]);                            \
            }                                                                   \
        }                                                                       \
        _Pragma("unroll")                                                       \
        for (int j = 0; j < 4; ++j) {                                           \
            int px = r1 * 16 + g1 * 4 + j;                                      \
            *(unsigned int*)(w1 + swz(px, cp1 * 4)) = cvt_pk_bf16(B0[j], B1[j]);\
        }                                                                       \
    }

#define MFMA_PHASE(buf)                                                         \
    {                                                                           \
        const char* r2 = (const char*)&f2s[(buf)][0];                           \
        const char* r1p = (const char*)&f1s[(buf)][0];                          \
        bf16x8 af = *(const bf16x8*)(r1p + aOff);                               \
        _Pragma("unroll")                                                       \
        for (int dy = 0; dy < 9; ++dy) {                                        \
            int pb = (wave + dy) * WCOL + col;                                  \
            bf16x8 b0 = *(const bf16x8*)(r2 + swz(pb, quad * 16));              \
            bf16x8 b1 = *(const bf16x8*)(r2 + swz(pb + 16, quad * 16));         \
            acc[dy][0] = __builtin_amdgcn_mfma_f32_16x16x32_bf16(af, b0, acc[dy][0], 0, 0, 0); \
            acc[dy][1] = __builtin_amdgcn_mfma_f32_16x16x32_bf16(af, b1, acc[dy][1], 0, 0, 0); \
        }                                                                       \
    }

#define NORM_PHASE(buf)                                                         \
    {                                                                           \
        const char* r2 = (const char*)&f2s[(buf)][0];                           \
        const char* r1p = (const char*)&f1s[(buf)][0];                          \
        _Pragma("unroll")                                                       \
        for (int j = 0; j < 4; ++j) {                                           \
            u32x4 v = *(const u32x4*)(r2 + swz(tid, j * 16));                   \
            dot2_sq(v[0], ss2); dot2_sq(v[1], ss2);                             \
            dot2_sq(v[2], ss2); dot2_sq(v[3], ss2);                             \
        }                                                                       \
        u32x4 v = *(const u32x4*)(r1p + swz(tid >> 2, (tid & 3) * 16));         \
        dot2_sq(v[0], ss1); dot2_sq(v[1], ss1);                                 \
        dot2_sq(v[2], ss1); dot2_sq(v[3], ss1);                                 \
    }

    // ---- prologue: stage chunk 0 into buf0, issue chunk-1 loads ----
    ISSUE_LOADS(0);
    PACK_WRITE(0);
    ISSUE_LOADS(KC);
    BARRIER();

    // ---- main: one barrier per chunk; loads fly across barriers ----
#pragma unroll
    for (int k = 0; k < NCHUNK; ++k) {
        const int bk = k & 1;
        MFMA_PHASE(bk);
        if (k < NCHUNK - 1) {
            PACK_WRITE(bk ^ 1);            // consumes prefetch regs (WAR before re-issue)
            if (k < NCHUNK - 2) ISSUE_LOADS((k + 2) * KC);
            NORM_PHASE(bk);
        } else {
            NORM_PHASE(bk);
            invn2[tid] = 1.f / fmaxf(sqrtf(ss2), 1e-12f);
            float t1 = ss1 + __shfl_xor(ss1, 1);
            t1 += __shfl_xor(t1, 2);
            if ((tid & 3) == 0) invn1[tid >> 2] = 1.f / fmaxf(sqrtf(t1), 1e-12f);
        }
        BARRIER();
    }

    // ---- epilogue: extract band, rescale, leaky-relu, store ----
    const int hOut = h0 + wave;
    float* outB = out + (size_t)b * ND * HW_ + (size_t)hOut * W_;
    const float scale = 1.f / (float)C_;

#pragma unroll
    for (int dy = 0; dy < 9; ++dy) {
        int hr = wave + dy;
#pragma unroll
        for (int t = 0; t < 2; ++t) {
            float i2 = invn2[hr * WCOL + t * 16 + col];
#pragma unroll
            for (int r = 0; r < 4; ++r) {
                int row = quad * 4 + r;
                int dx = t * 16 + col - row;
                if (dx >= 0 && dx <= 8) {
                    float v = acc[dy][t][r] * invn1[wave * 16 + row] * i2 * scale;
                    v = (v >= 0.f) ? v : 0.1f * v;
                    outB[(size_t)(dy * 9 + dx) * HW_ + (w0 + row)] = v;
                }
            }
        }
    }
#undef ISSUE_LOADS
#undef PACK_WRITE
#undef MFMA_PHASE
#undef NORM_PHASE
}

extern "C" void kernel_launch(void* const* d_in, const int* in_sizes, int n_in,
                              void* d_out, int out_size, void* d_ws, size_t ws_size,
                              hipStream_t stream) {
    const float* f1 = (const float*)d_in[0];
    const float* f2 = (const float*)d_in[1];
    float* out = (float*)d_out;
    dim3 grid(W_ / TW, H_ / TH, B_);   // 16 x 16 x 4 = 1024 blocks
    corr81_kernel<<<grid, NTHREADS, 0, stream>>>(f1, f2, out);
}